// Round 9
// baseline (986.852 us; speedup 1.0000x reference)
//
#include <hip/hip_runtime.h>
#include <hip/hip_bf16.h>

#define N_NODES 50000
#define N_EDGES 800000
#define ETOT    (N_EDGES + N_NODES)
#define DIM     256
#define NEG_SLOPE 0.2f

typedef __attribute__((ext_vector_type(4))) float  floatx4;
typedef __attribute__((ext_vector_type(8))) short  shortx8;
typedef __attribute__((ext_vector_type(4))) short  shortx4;

__device__ inline float bf2f(unsigned short u) {
    union { unsigned int i; float f; } c; c.i = ((unsigned int)u) << 16; return c.f;
}
__device__ inline unsigned short f2bf(float x) {
    union { float f; unsigned int i; } c; c.f = x;
    unsigned int r = c.i + 0x7FFF + ((c.i >> 16) & 1);
    return (unsigned short)(r >> 16);
}

// ---------------- dtype detection ----------------
__global__ void detect_kernel(const unsigned short* __restrict__ xs,
                              const int* __restrict__ ei, int* __restrict__ flags) {
    int tid = threadIdx.x;
    unsigned short s = xs[2 * tid];
    float av = fabsf(bf2f(s));
    int hit = (av > 0.001f && av < 100.0f) ? 1 : 0;
    int odd = ei[2 * tid + 1];
    __shared__ int sh_hit[256], sh_nz[256];
    sh_hit[tid] = hit; sh_nz[tid] = (odd != 0) ? 1 : 0;
    __syncthreads();
    for (int st = 128; st > 0; st >>= 1) {
        if (tid < st) { sh_hit[tid] += sh_hit[tid + st]; sh_nz[tid] += sh_nz[tid + st]; }
        __syncthreads();
    }
    if (tid == 0) {
        flags[0] = (sh_hit[0] < 128) ? 1 : 0;   // 1 = fp32 floats
        flags[1] = (sh_nz[0] == 0) ? 1 : 0;     // 1 = int64 edge_index
    }
}

// ---------------- input normalization ----------------
__global__ void norm_x(const void* __restrict__ src, unsigned short* __restrict__ dst,
                       const int* __restrict__ flags) {
    int i = (blockIdx.x * 256 + threadIdx.x) * 4;
    if (flags[0]) {
        const float* s = (const float*)src;
        dst[i + 0] = f2bf(s[i + 0]); dst[i + 1] = f2bf(s[i + 1]);
        dst[i + 2] = f2bf(s[i + 2]); dst[i + 3] = f2bf(s[i + 3]);
    } else {
        *(shortx4*)(dst + i) = *(const shortx4*)((const unsigned short*)src + i);
    }
}

__global__ void norm_small(const void* __restrict__ src, unsigned short* __restrict__ dst,
                           int count, const int* __restrict__ flags) {
    int i = blockIdx.x * 256 + threadIdx.x;
    if (i >= count) return;
    dst[i] = flags[0] ? f2bf(((const float*)src)[i]) : ((const unsigned short*)src)[i];
}

__global__ void norm_edges(const int* __restrict__ ei, int* __restrict__ rown,
                           int* __restrict__ coln, const int* __restrict__ flags) {
    int e = blockIdx.x * 256 + threadIdx.x;
    if (e >= N_EDGES) return;
    if (flags[1]) { rown[e] = ei[2 * e]; coln[e] = ei[2 * (N_EDGES + e)]; }
    else          { rown[e] = ei[e];     coln[e] = ei[N_EDGES + e]; }
}

// ---------------- weight transpose (5 x [256,256] -> B^T bf16) ----------------
__global__ void transpose_kernel(const void* __restrict__ W1, const void* __restrict__ W2,
                                 const void* __restrict__ Wb, unsigned short* __restrict__ BT,
                                 const int* __restrict__ flags) {
    int idx = blockIdx.x * 256 + threadIdx.x;   // < 5*65536
    int m = idx >> 16, rem = idx & 65535;
    int k = rem >> 8, nn = rem & 255;
    const void* src = (m == 0) ? W1 : ((m == 1) ? W2 : Wb);
    size_t el = (m >= 2) ? ((size_t)(m - 2) * 65536 + rem) : (size_t)rem;
    unsigned short val = flags[0] ? f2bf(((const float*)src)[el])
                                  : ((const unsigned short*)src)[el];
    BT[(size_t)m * 65536 + nn * 256 + k] = val;
}

// ---------------- CSR build (generic over key array) ----------------
__global__ void zero_kernel(int* p, int n) {
    int i = blockIdx.x * 256 + threadIdx.x;
    if (i < n) p[i] = 0;
}

__global__ void count_kernel(const int* __restrict__ coln, int* __restrict__ cnt) {
    int e = blockIdx.x * 256 + threadIdx.x;
    if (e >= ETOT) return;
    int c = (e < N_EDGES) ? coln[e] : (e - N_EDGES);
    atomicAdd(&cnt[c], 1);
}

__global__ void count_src(const int* __restrict__ rown, int* __restrict__ cnt) {
    int e = blockIdx.x * 256 + threadIdx.x;
    if (e >= N_EDGES) return;
    atomicAdd(&cnt[rown[e]], 1);
}

__global__ void scan_kernel(const int* __restrict__ cnt, int* __restrict__ off) {
    __shared__ int buf[1024];
    __shared__ int carry;
    if (threadIdx.x == 0) carry = 0;
    __syncthreads();
    for (int base = 0; base < N_NODES; base += 1024) {
        int i = base + threadIdx.x;
        int v = (i < N_NODES) ? cnt[i] : 0;
        buf[threadIdx.x] = v;
        __syncthreads();
        for (int s = 1; s < 1024; s <<= 1) {
            int t = (threadIdx.x >= s) ? buf[threadIdx.x - s] : 0;
            __syncthreads();
            buf[threadIdx.x] += t;
            __syncthreads();
        }
        int incl = buf[threadIdx.x];
        int total = buf[1023];
        if (i < N_NODES) off[i] = carry + incl - v;
        __syncthreads();
        if (threadIdx.x == 0) carry += total;
        __syncthreads();
    }
    if (threadIdx.x == 0) off[N_NODES] = carry;
}

__global__ void fill_kernel(const int* __restrict__ coln, const int* __restrict__ off,
                            int* __restrict__ cursor, int* __restrict__ eidx) {
    int e = blockIdx.x * 256 + threadIdx.x;
    if (e >= ETOT) return;
    int c = (e < N_EDGES) ? coln[e] : (e - N_EDGES);
    int p = atomicAdd(&cursor[c], 1);
    eidx[off[c] + p] = e;
}

__global__ void fill_src(const int* __restrict__ rown, const int* __restrict__ off,
                         int* __restrict__ cursor, int* __restrict__ eidx) {
    int e = blockIdx.x * 256 + threadIdx.x;
    if (e >= N_EDGES) return;
    int c = rown[e];
    int p = atomicAdd(&cursor[c], 1);
    eidx[off[c] + p] = e;
}

// ---------------- bf16 MFMA GEMM: C[M,Nc] = A[M,256] * B (BT given, Nc cols) ----------------
__global__ __launch_bounds__(256) void gemm256(
    const unsigned short* __restrict__ A,
    const unsigned short* __restrict__ BT,
    unsigned short* __restrict__ Cb, int M, int Nc)
{
    __shared__ short As[128 * 32];
    __shared__ short Bs[128 * 32];
    int tid = threadIdx.x, lane = tid & 63, wave = tid >> 6;
    int wm = wave & 1, wn = wave >> 1;
    int m0 = blockIdx.x * 128, n0 = blockIdx.y * 128;
    floatx4 acc[4][4] = {};
    for (int k0 = 0; k0 < 256; k0 += 32) {
        __syncthreads();
#pragma unroll
        for (int i = 0; i < 2; i++) {
            int c = i * 256 + tid;
            int row = c >> 2, koff = (c & 3) * 8;
            int gr = m0 + row; if (gr > M - 1) gr = M - 1;
            shortx8 av = *(const shortx8*)(A + (size_t)gr * 256 + k0 + koff);
            *(shortx8*)(As + row * 32 + koff) = av;
            int gn = n0 + row;
            shortx8 bv = *(const shortx8*)(BT + (size_t)gn * 256 + k0 + koff);
            *(shortx8*)(Bs + row * 32 + koff) = bv;
        }
        __syncthreads();
        shortx8 af[4], bfr[4];
#pragma unroll
        for (int mt = 0; mt < 4; mt++)
            af[mt] = *(const shortx8*)(As + (wm * 64 + mt * 16 + (lane & 15)) * 32 + (lane >> 4) * 8);
#pragma unroll
        for (int nt = 0; nt < 4; nt++)
            bfr[nt] = *(const shortx8*)(Bs + (wn * 64 + nt * 16 + (lane & 15)) * 32 + (lane >> 4) * 8);
#pragma unroll
        for (int mt = 0; mt < 4; mt++)
#pragma unroll
            for (int nt = 0; nt < 4; nt++)
                acc[mt][nt] = __builtin_amdgcn_mfma_f32_16x16x32_bf16(af[mt], bfr[nt], acc[mt][nt], 0, 0, 0);
    }
#pragma unroll
    for (int mt = 0; mt < 4; mt++) {
#pragma unroll
        for (int r = 0; r < 4; r++) {
            int grow = m0 + wm * 64 + mt * 16 + (lane >> 4) * 4 + r;
            if (grow >= M) continue;
#pragma unroll
            for (int nt = 0; nt < 4; nt++) {
                int gcol = n0 + wn * 64 + nt * 16 + (lane & 15);
                Cb[(size_t)grow * Nc + gcol] = f2bf(acc[mt][nt][r]);
            }
        }
    }
}

// ---------------- attention scores (wave per node) ----------------
__global__ __launch_bounds__(256) void s_kernel(
    const unsigned short* __restrict__ xw,
    const unsigned short* __restrict__ a_src,
    const unsigned short* __restrict__ a_dst,
    float* __restrict__ s_src, float* __restrict__ s_dst)
{
    int wid = (blockIdx.x * 256 + threadIdx.x) >> 6;
    int lane = threadIdx.x & 63;
    if (wid >= N_NODES) return;
    int f = lane * 4;
    shortx4 xv = *(const shortx4*)(xw + (size_t)wid * DIM + f);
    shortx4 asv = *(const shortx4*)(a_src + f);
    shortx4 adv = *(const shortx4*)(a_dst + f);
    float x0 = bf2f((unsigned short)xv.x), x1 = bf2f((unsigned short)xv.y);
    float x2 = bf2f((unsigned short)xv.z), x3 = bf2f((unsigned short)xv.w);
    float ps = x0 * bf2f((unsigned short)asv.x) + x1 * bf2f((unsigned short)asv.y)
             + x2 * bf2f((unsigned short)asv.z) + x3 * bf2f((unsigned short)asv.w);
    float pd = x0 * bf2f((unsigned short)adv.x) + x1 * bf2f((unsigned short)adv.y)
             + x2 * bf2f((unsigned short)adv.z) + x3 * bf2f((unsigned short)adv.w);
    for (int s = 1; s < 16; s <<= 1) { ps += __shfl_xor(ps, s); pd += __shfl_xor(pd, s); }
    if ((lane & 15) == 0) {
        int h = lane >> 4;
        s_src[(size_t)wid * 4 + h] = ps;
        s_dst[(size_t)wid * 4 + h] = pd;
    }
}

// ---------------- fused per-node online-softmax + aggregation (one wave per node) ----------------
// layer 1: h_bf written.  layer 2: h_bf + h_f32 + node_pred fused (wn != null).
__global__ __launch_bounds__(256) void attn_agg(
    const unsigned short* __restrict__ xw,
    const float* __restrict__ s_src, const float* __restrict__ s_dst,
    const int* __restrict__ off, const int* __restrict__ eidx,
    const int* __restrict__ rown, const unsigned short* __restrict__ bias,
    unsigned short* __restrict__ h_bf, float* __restrict__ h_f32,
    float* __restrict__ attn_acc, float* __restrict__ attn_out,
    const unsigned short* __restrict__ wn, const unsigned short* __restrict__ bn,
    float* __restrict__ node_out, int layer)
{
    int wid = (blockIdx.x * 256 + threadIdx.x) >> 6;
    int lane = threadIdx.x & 63;
    if (wid >= N_NODES) return;
    int n = wid;
    floatx4 sdv = *(const floatx4*)(s_dst + (size_t)n * 4);
    int base = off[n];
    int deg = off[n + 1] - base;

    // online (max, denom)
    float m0 = -1e30f, m1 = -1e30f, m2 = -1e30f, m3 = -1e30f;
    float d0 = 0.f, d1 = 0.f, d2 = 0.f, d3 = 0.f;
    for (int i = lane; i < deg; i += 64) {
        int e = eidx[base + i];
        int r = (e < N_EDGES) ? rown[e] : (e - N_EDGES);
        floatx4 sv = *(const floatx4*)(s_src + (size_t)r * 4);
        float t0 = sv.x + sdv.x; t0 = t0 > 0.f ? t0 : NEG_SLOPE * t0;
        float t1 = sv.y + sdv.y; t1 = t1 > 0.f ? t1 : NEG_SLOPE * t1;
        float t2 = sv.z + sdv.z; t2 = t2 > 0.f ? t2 : NEG_SLOPE * t2;
        float t3 = sv.w + sdv.w; t3 = t3 > 0.f ? t3 : NEG_SLOPE * t3;
        float nm;
        nm = fmaxf(m0, t0); d0 = d0 * __expf(m0 - nm) + __expf(t0 - nm); m0 = nm;
        nm = fmaxf(m1, t1); d1 = d1 * __expf(m1 - nm) + __expf(t1 - nm); m1 = nm;
        nm = fmaxf(m2, t2); d2 = d2 * __expf(m2 - nm) + __expf(t2 - nm); m2 = nm;
        nm = fmaxf(m3, t3); d3 = d3 * __expf(m3 - nm) + __expf(t3 - nm); m3 = nm;
    }
    for (int s = 1; s < 64; s <<= 1) {
        float om, od, nm;
        om = __shfl_xor(m0, s); od = __shfl_xor(d0, s);
        nm = fmaxf(m0, om); d0 = d0 * __expf(m0 - nm) + od * __expf(om - nm); m0 = nm;
        om = __shfl_xor(m1, s); od = __shfl_xor(d1, s);
        nm = fmaxf(m1, om); d1 = d1 * __expf(m1 - nm) + od * __expf(om - nm); m1 = nm;
        om = __shfl_xor(m2, s); od = __shfl_xor(d2, s);
        nm = fmaxf(m2, om); d2 = d2 * __expf(m2 - nm) + od * __expf(om - nm); m2 = nm;
        om = __shfl_xor(m3, s); od = __shfl_xor(d3, s);
        nm = fmaxf(m3, om); d3 = d3 * __expf(m3 - nm) + od * __expf(om - nm); m3 = nm;
    }
    float i0 = 1.f / d0, i1 = 1.f / d1, i2 = 1.f / d2, i3 = 1.f / d3;

    // alpha + weighted feature gather
    int hl = lane >> 4;
    int f = lane * 4;
    float acc0 = 0.f, acc1 = 0.f, acc2 = 0.f, acc3 = 0.f;
    for (int c0 = 0; c0 < deg; c0 += 64) {
        int i = c0 + lane;
        int r = 0; float a0 = 0.f, a1 = 0.f, a2 = 0.f, a3 = 0.f;
        if (i < deg) {
            int e = eidx[base + i];
            r = (e < N_EDGES) ? rown[e] : (e - N_EDGES);
            floatx4 sv = *(const floatx4*)(s_src + (size_t)r * 4);
            float t0 = sv.x + sdv.x; t0 = t0 > 0.f ? t0 : NEG_SLOPE * t0;
            float t1 = sv.y + sdv.y; t1 = t1 > 0.f ? t1 : NEG_SLOPE * t1;
            float t2 = sv.z + sdv.z; t2 = t2 > 0.f ? t2 : NEG_SLOPE * t2;
            float t3 = sv.w + sdv.w; t3 = t3 > 0.f ? t3 : NEG_SLOPE * t3;
            a0 = __expf(t0 - m0) * i0; a1 = __expf(t1 - m1) * i1;
            a2 = __expf(t2 - m2) * i2; a3 = __expf(t3 - m3) * i3;
            float suma = 0.125f * (a0 + a1 + a2 + a3);
            if (layer == 0) attn_acc[e] = suma;
            else            attn_out[e] = attn_acc[e] + suma;
        }
        int cntc = deg - c0; if (cntc > 64) cntc = 64;
        for (int j = 0; j < cntc; j++) {
            int rj = __shfl(r, j);
            float b0 = __shfl(a0, j), b1 = __shfl(a1, j), b2 = __shfl(a2, j), b3 = __shfl(a3, j);
            float al = (hl == 0) ? b0 : ((hl == 1) ? b1 : ((hl == 2) ? b2 : b3));
            shortx4 xv = *(const shortx4*)(xw + (size_t)rj * DIM + f);
            acc0 += al * bf2f((unsigned short)xv.x);
            acc1 += al * bf2f((unsigned short)xv.y);
            acc2 += al * bf2f((unsigned short)xv.z);
            acc3 += al * bf2f((unsigned short)xv.w);
        }
    }
    shortx4 bv = *(const shortx4*)(bias + f);
    float o0 = acc0 + bf2f((unsigned short)bv.x);
    float o1 = acc1 + bf2f((unsigned short)bv.y);
    float o2 = acc2 + bf2f((unsigned short)bv.z);
    float o3 = acc3 + bf2f((unsigned short)bv.w);
    o0 = o0 > 0.f ? o0 : (__expf(o0) - 1.f);
    o1 = o1 > 0.f ? o1 : (__expf(o1) - 1.f);
    o2 = o2 > 0.f ? o2 : (__expf(o2) - 1.f);
    o3 = o3 > 0.f ? o3 : (__expf(o3) - 1.f);
    if (h_bf) {
        shortx4 pk;
        pk.x = (short)f2bf(o0); pk.y = (short)f2bf(o1);
        pk.z = (short)f2bf(o2); pk.w = (short)f2bf(o3);
        *(shortx4*)(h_bf + (size_t)n * DIM + f) = pk;
    }
    if (h_f32) {
        floatx4 pv; pv.x = o0; pv.y = o1; pv.z = o2; pv.w = o3;
        *(floatx4*)(h_f32 + (size_t)n * DIM + f) = pv;
    }
    if (wn) {   // fused node predictor
        shortx4 wv = *(const shortx4*)(wn + f);
        float p = o0 * bf2f((unsigned short)wv.x) + o1 * bf2f((unsigned short)wv.y)
                + o2 * bf2f((unsigned short)wv.z) + o3 * bf2f((unsigned short)wv.w);
        for (int s = 1; s < 64; s <<= 1) p += __shfl_xor(p, s);
        if (lane == 0) node_out[n] = p + bf2f(bn[0]);
    }
}

// ---------------- edge predictor, source-CSR: one wave per source node ----------------
__global__ __launch_bounds__(256) void edge_pred_src(
    const unsigned short* __restrict__ h,   // bf16 [N,256]
    const unsigned short* __restrict__ V,   // bf16 [N,768] = V0|V1|V2
    const int* __restrict__ soff, const int* __restrict__ seidx,
    const int* __restrict__ coln,
    const unsigned short* __restrict__ bb, float* __restrict__ outp)
{
    int wid = (blockIdx.x * 256 + threadIdx.x) >> 6;
    int lane = threadIdx.x & 63;
    if (wid >= N_NODES) return;
    int s = wid;
    int base = soff[s];
    int deg = soff[s + 1] - base;
    if (deg == 0) return;
    int f = lane * 4;
    // load V[s] fragments once (3 x shortx4 per lane)
    const unsigned short* vrow = V + (size_t)s * 768;
    shortx4 v0 = *(const shortx4*)(vrow + 0   + f);
    shortx4 v1 = *(const shortx4*)(vrow + 256 + f);
    shortx4 v2 = *(const shortx4*)(vrow + 512 + f);
    float w00 = bf2f((unsigned short)v0.x), w01 = bf2f((unsigned short)v0.y),
          w02 = bf2f((unsigned short)v0.z), w03 = bf2f((unsigned short)v0.w);
    float w10 = bf2f((unsigned short)v1.x), w11 = bf2f((unsigned short)v1.y),
          w12 = bf2f((unsigned short)v1.z), w13 = bf2f((unsigned short)v1.w);
    float w20 = bf2f((unsigned short)v2.x), w21 = bf2f((unsigned short)v2.y),
          w22 = bf2f((unsigned short)v2.z), w23 = bf2f((unsigned short)v2.w);
    float bb0 = bf2f(bb[0]), bb1 = bf2f(bb[1]), bb2 = bf2f(bb[2]);
    for (int i = 0; i < deg; i++) {
        int e = seidx[base + i];
        int t = coln[e];
        shortx4 hv = *(const shortx4*)(h + (size_t)t * DIM + f);
        float h0 = bf2f((unsigned short)hv.x), h1 = bf2f((unsigned short)hv.y);
        float h2 = bf2f((unsigned short)hv.z), h3 = bf2f((unsigned short)hv.w);
        float p0 = h0 * w00 + h1 * w01 + h2 * w02 + h3 * w03;
        float p1 = h0 * w10 + h1 * w11 + h2 * w12 + h3 * w13;
        float p2 = h0 * w20 + h1 * w21 + h2 * w22 + h3 * w23;
        for (int m = 1; m < 64; m <<= 1) {
            p0 += __shfl_xor(p0, m);
            p1 += __shfl_xor(p1, m);
            p2 += __shfl_xor(p2, m);
        }
        if (lane == 0) {
            outp[(size_t)e * 3 + 0] = p0 + bb0;
            outp[(size_t)e * 3 + 1] = p1 + bb1;
            outp[(size_t)e * 3 + 2] = p2 + bb2;
        }
    }
}

extern "C" void kernel_launch(void* const* d_in, const int* in_sizes, int n_in,
                              void* d_out, int out_size, void* d_ws, size_t ws_size,
                              hipStream_t stream) {
    const void* x_raw  = d_in[0];
    const int*  ei_raw = (const int*)d_in[1];
    float* out = (float*)d_out;

    char* w = (char*)d_ws;
    size_t off_b = 0;
    auto alloc = [&](size_t bytes) -> char* {
        char* p = w + off_b; off_b = (off_b + bytes + 255) & ~(size_t)255; return p;
    };
    int*            flags  = (int*)alloc(256);
    unsigned short* buf0   = (unsigned short*)alloc((size_t)N_NODES * DIM * 2); // x_bf -> h bf16
    unsigned short* R      = (unsigned short*)alloc((size_t)N_NODES * 768 * 2); // xw|h1, later V
    unsigned short* buf1   = R;
    unsigned short* buf2   = R + (size_t)N_NODES * DIM;
    unsigned short* V      = R;
    float*          ssrc   = (float*)alloc((size_t)N_NODES * 4 * 4);
    float*          sdst   = (float*)alloc((size_t)N_NODES * 4 * 4);
    float*          attn   = (float*)alloc((size_t)ETOT * 4);
    int*            cnt    = (int*)alloc((size_t)4 * N_NODES * 4);  // cnt,cursor,scnt,scursor
    int*            cursor = cnt + N_NODES;
    int*            scnt   = cnt + 2 * N_NODES;
    int*            scursor= cnt + 3 * N_NODES;
    int*            offs   = (int*)alloc((size_t)(N_NODES + 1) * 4);
    int*            soffs  = (int*)alloc((size_t)(N_NODES + 1) * 4);
    int*            eidx   = (int*)alloc((size_t)ETOT * 4);
    int*            seidx  = (int*)alloc((size_t)N_EDGES * 4);
    int*            rown   = (int*)alloc((size_t)N_EDGES * 4);
    int*            coln   = (int*)alloc((size_t)N_EDGES * 4);
    unsigned short* BT     = (unsigned short*)alloc((size_t)5 * 65536 * 2);
    unsigned short* small  = (unsigned short*)alloc(2048 * 2);
    // small: a1s@0 a1d@256 b1@512 a2s@768 a2d@1024 b2@1280 Wn@1536 bn@1792 bb@1793

    float* out_node = out;              // [50000]
    float* out_edge = out + 50000;      // [800000,3]
    float* out_h    = out + 2450000;    // [50000,256]
    float* out_attn = out + 15250000;   // [850000]

    int eb = (ETOT + 255) / 256;
    int e0b = (N_EDGES + 255) / 256;
    int node_wave_blocks = (N_NODES * 64) / 256;
    dim3 gg((N_NODES + 127) / 128, 2);
    dim3 gv((N_NODES + 127) / 128, 6);

    detect_kernel<<<1, 256, 0, stream>>>((const unsigned short*)x_raw, ei_raw, flags);
    norm_x<<<12500, 256, 0, stream>>>(x_raw, buf0, flags);
    norm_small<<<1, 256, 0, stream>>>(d_in[3],  small + 0,    256, flags);
    norm_small<<<1, 256, 0, stream>>>(d_in[4],  small + 256,  256, flags);
    norm_small<<<1, 256, 0, stream>>>(d_in[5],  small + 512,  256, flags);
    norm_small<<<1, 256, 0, stream>>>(d_in[7],  small + 768,  256, flags);
    norm_small<<<1, 256, 0, stream>>>(d_in[8],  small + 1024, 256, flags);
    norm_small<<<1, 256, 0, stream>>>(d_in[9],  small + 1280, 256, flags);
    norm_small<<<1, 256, 0, stream>>>(d_in[10], small + 1536, 256, flags);
    norm_small<<<1, 256, 0, stream>>>(d_in[11], small + 1792, 1,   flags);
    norm_small<<<1, 256, 0, stream>>>(d_in[13], small + 1793, 3,   flags);
    norm_edges<<<3125, 256, 0, stream>>>(ei_raw, rown, coln, flags);
    transpose_kernel<<<1280, 256, 0, stream>>>(d_in[2], d_in[6], d_in[12], BT, flags);

    zero_kernel<<<(4 * N_NODES + 255) / 256, 256, 0, stream>>>(cnt, 4 * N_NODES);
    count_kernel<<<eb, 256, 0, stream>>>(coln, cnt);
    scan_kernel<<<1, 1024, 0, stream>>>(cnt, offs);
    fill_kernel<<<eb, 256, 0, stream>>>(coln, offs, cursor, eidx);
    count_src<<<e0b, 256, 0, stream>>>(rown, scnt);
    scan_kernel<<<1, 1024, 0, stream>>>(scnt, soffs);
    fill_src<<<e0b, 256, 0, stream>>>(rown, soffs, scursor, seidx);

    // ---- layer 1 ----
    gemm256<<<gg, 256, 0, stream>>>(buf0, BT, buf1, N_NODES, 256);
    s_kernel<<<node_wave_blocks, 256, 0, stream>>>(buf1, small + 0, small + 256, ssrc, sdst);
    attn_agg<<<node_wave_blocks, 256, 0, stream>>>(buf1, ssrc, sdst, offs, eidx, rown,
                                                   small + 512, buf2, nullptr, attn, nullptr,
                                                   nullptr, nullptr, nullptr, 0);

    // ---- layer 2 (+ fused node_pred) ----
    gemm256<<<gg, 256, 0, stream>>>(buf2, BT + 65536, buf1, N_NODES, 256);
    s_kernel<<<node_wave_blocks, 256, 0, stream>>>(buf1, small + 768, small + 1024, ssrc, sdst);
    attn_agg<<<node_wave_blocks, 256, 0, stream>>>(buf1, ssrc, sdst, offs, eidx, rown,
                                                   small + 1280, buf0, out_h, attn, out_attn,
                                                   small + 1536, small + 1792, out_node, 1);

    // ---- edge head: V[N,768] in one GEMM; source-CSR edge dots ----
    gemm256<<<gv, 256, 0, stream>>>(buf0, BT + 2 * 65536, V, N_NODES, 768);
    edge_pred_src<<<node_wave_blocks, 256, 0, stream>>>(buf0, V, soffs, seidx, coln,
                                                        small + 1793, out_edge);
}

// Round 10
// 806.637 us; speedup vs baseline: 1.2234x; 1.2234x over previous
//
#include <hip/hip_runtime.h>
#include <hip/hip_bf16.h>

#define N_NODES 50000
#define N_EDGES 800000
#define ETOT    (N_EDGES + N_NODES)
#define DIM     256
#define NEG_SLOPE 0.2f
#define NBLK    ((N_NODES + 255) / 256)

typedef __attribute__((ext_vector_type(4))) float  floatx4;
typedef __attribute__((ext_vector_type(8))) short  shortx8;
typedef __attribute__((ext_vector_type(4))) short  shortx4;

__device__ inline float bf2f(unsigned short u) {
    union { unsigned int i; float f; } c; c.i = ((unsigned int)u) << 16; return c.f;
}
__device__ inline unsigned short f2bf(float x) {
    union { float f; unsigned int i; } c; c.f = x;
    unsigned int r = c.i + 0x7FFF + ((c.i >> 16) & 1);
    return (unsigned short)(r >> 16);
}

// ---------------- dtype detection ----------------
__global__ void detect_kernel(const unsigned short* __restrict__ xs,
                              const int* __restrict__ ei, int* __restrict__ flags) {
    int tid = threadIdx.x;
    unsigned short s = xs[2 * tid];
    float av = fabsf(bf2f(s));
    int hit = (av > 0.001f && av < 100.0f) ? 1 : 0;
    int odd = ei[2 * tid + 1];
    __shared__ int sh_hit[256], sh_nz[256];
    sh_hit[tid] = hit; sh_nz[tid] = (odd != 0) ? 1 : 0;
    __syncthreads();
    for (int st = 128; st > 0; st >>= 1) {
        if (tid < st) { sh_hit[tid] += sh_hit[tid + st]; sh_nz[tid] += sh_nz[tid + st]; }
        __syncthreads();
    }
    if (tid == 0) {
        flags[0] = (sh_hit[0] < 128) ? 1 : 0;   // 1 = fp32 floats
        flags[1] = (sh_nz[0] == 0) ? 1 : 0;     // 1 = int64 edge_index
    }
}

// ---------------- input normalization ----------------
__global__ void norm_x(const void* __restrict__ src, unsigned short* __restrict__ dst,
                       const int* __restrict__ flags) {
    int i = (blockIdx.x * 256 + threadIdx.x) * 4;
    if (flags[0]) {
        const float* s = (const float*)src;
        dst[i + 0] = f2bf(s[i + 0]); dst[i + 1] = f2bf(s[i + 1]);
        dst[i + 2] = f2bf(s[i + 2]); dst[i + 3] = f2bf(s[i + 3]);
    } else {
        *(shortx4*)(dst + i) = *(const shortx4*)((const unsigned short*)src + i);
    }
}

__global__ void norm_small(const void* __restrict__ src, unsigned short* __restrict__ dst,
                           int count, const int* __restrict__ flags) {
    int i = blockIdx.x * 256 + threadIdx.x;
    if (i >= count) return;
    dst[i] = flags[0] ? f2bf(((const float*)src)[i]) : ((const unsigned short*)src)[i];
}

__global__ void norm_edges(const int* __restrict__ ei, int* __restrict__ rown,
                           int* __restrict__ coln, const int* __restrict__ flags) {
    int e = blockIdx.x * 256 + threadIdx.x;
    if (e >= N_EDGES) return;
    if (flags[1]) { rown[e] = ei[2 * e]; coln[e] = ei[2 * (N_EDGES + e)]; }
    else          { rown[e] = ei[e];     coln[e] = ei[N_EDGES + e]; }
}

// ---------------- weight transpose (5 x [256,256] -> B^T bf16) ----------------
__global__ void transpose_kernel(const void* __restrict__ W1, const void* __restrict__ W2,
                                 const void* __restrict__ Wb, unsigned short* __restrict__ BT,
                                 const int* __restrict__ flags) {
    int idx = blockIdx.x * 256 + threadIdx.x;   // < 5*65536
    int m = idx >> 16, rem = idx & 65535;
    int k = rem >> 8, nn = rem & 255;
    const void* src = (m == 0) ? W1 : ((m == 1) ? W2 : Wb);
    size_t el = (m >= 2) ? ((size_t)(m - 2) * 65536 + rem) : (size_t)rem;
    unsigned short val = flags[0] ? f2bf(((const float*)src)[el])
                                  : ((const unsigned short*)src)[el];
    BT[(size_t)m * 65536 + nn * 256 + k] = val;
}

// ---------------- CSR build ----------------
__global__ void zero_kernel(int* p, int n) {
    int i = blockIdx.x * 256 + threadIdx.x;
    if (i < n) p[i] = 0;
}

__global__ void count_kernel(const int* __restrict__ coln, int* __restrict__ cnt) {
    int e = blockIdx.x * 256 + threadIdx.x;
    if (e >= ETOT) return;
    int c = (e < N_EDGES) ? coln[e] : (e - N_EDGES);
    atomicAdd(&cnt[c], 1);
}

__global__ void count_src(const int* __restrict__ rown, int* __restrict__ cnt) {
    int e = blockIdx.x * 256 + threadIdx.x;
    if (e >= N_EDGES) return;
    atomicAdd(&cnt[rown[e]], 1);
}

// hierarchical scan: part sums -> small scan -> add-back
__global__ void scan_part(const int* __restrict__ cnt, int* __restrict__ part, int n) {
    __shared__ int sh[256];
    int t = threadIdx.x;
    int i = blockIdx.x * 256 + t;
    sh[t] = (i < n) ? cnt[i] : 0;
    __syncthreads();
    for (int s = 128; s > 0; s >>= 1) {
        if (t < s) sh[t] += sh[t + s];
        __syncthreads();
    }
    if (t == 0) part[blockIdx.x] = sh[0];
}

__global__ void scan_small(int* __restrict__ part, int n) {   // exclusive, in place (n<=256)
    __shared__ int sh[256];
    int t = threadIdx.x;
    int v = (t < n) ? part[t] : 0;
    sh[t] = v;
    __syncthreads();
    for (int s = 1; s < 256; s <<= 1) {
        int u = (t >= s) ? sh[t - s] : 0;
        __syncthreads();
        sh[t] += u;
        __syncthreads();
    }
    if (t < n) part[t] = sh[t] - v;
}

__global__ void scan_final(const int* __restrict__ cnt, const int* __restrict__ part,
                           int* __restrict__ off, int n, int total) {
    __shared__ int sh[256];
    int t = threadIdx.x;
    int i = blockIdx.x * 256 + t;
    int v = (i < n) ? cnt[i] : 0;
    sh[t] = v;
    __syncthreads();
    for (int s = 1; s < 256; s <<= 1) {
        int u = (t >= s) ? sh[t - s] : 0;
        __syncthreads();
        sh[t] += u;
        __syncthreads();
    }
    if (i < n) off[i] = part[blockIdx.x] + sh[t] - v;
    if (i == 0) off[n] = total;
}

__global__ void fill_kernel(const int* __restrict__ coln, const int* __restrict__ off,
                            int* __restrict__ cursor, int* __restrict__ eidx) {
    int e = blockIdx.x * 256 + threadIdx.x;
    if (e >= ETOT) return;
    int c = (e < N_EDGES) ? coln[e] : (e - N_EDGES);
    int p = atomicAdd(&cursor[c], 1);
    eidx[off[c] + p] = e;
}

__global__ void fill_src(const int* __restrict__ rown, const int* __restrict__ off,
                         int* __restrict__ cursor, int* __restrict__ eidx) {
    int e = blockIdx.x * 256 + threadIdx.x;
    if (e >= N_EDGES) return;
    int c = rown[e];
    int p = atomicAdd(&cursor[c], 1);
    eidx[off[c] + p] = e;
}

// ---------------- bf16 MFMA GEMM: C[M,Nc] = A[M,256] * B (BT given, Nc cols) ----------------
__global__ __launch_bounds__(256) void gemm256(
    const unsigned short* __restrict__ A,
    const unsigned short* __restrict__ BT,
    unsigned short* __restrict__ Cb, int M, int Nc)
{
    __shared__ short As[128 * 32];
    __shared__ short Bs[128 * 32];
    int tid = threadIdx.x, lane = tid & 63, wave = tid >> 6;
    int wm = wave & 1, wn = wave >> 1;
    int m0 = blockIdx.x * 128, n0 = blockIdx.y * 128;
    floatx4 acc[4][4] = {};
    for (int k0 = 0; k0 < 256; k0 += 32) {
        __syncthreads();
#pragma unroll
        for (int i = 0; i < 2; i++) {
            int c = i * 256 + tid;
            int row = c >> 2, koff = (c & 3) * 8;
            int gr = m0 + row; if (gr > M - 1) gr = M - 1;
            shortx8 av = *(const shortx8*)(A + (size_t)gr * 256 + k0 + koff);
            *(shortx8*)(As + row * 32 + koff) = av;
            int gn = n0 + row;
            shortx8 bv = *(const shortx8*)(BT + (size_t)gn * 256 + k0 + koff);
            *(shortx8*)(Bs + row * 32 + koff) = bv;
        }
        __syncthreads();
        shortx8 af[4], bfr[4];
#pragma unroll
        for (int mt = 0; mt < 4; mt++)
            af[mt] = *(const shortx8*)(As + (wm * 64 + mt * 16 + (lane & 15)) * 32 + (lane >> 4) * 8);
#pragma unroll
        for (int nt = 0; nt < 4; nt++)
            bfr[nt] = *(const shortx8*)(Bs + (wn * 64 + nt * 16 + (lane & 15)) * 32 + (lane >> 4) * 8);
#pragma unroll
        for (int mt = 0; mt < 4; mt++)
#pragma unroll
            for (int nt = 0; nt < 4; nt++)
                acc[mt][nt] = __builtin_amdgcn_mfma_f32_16x16x32_bf16(af[mt], bfr[nt], acc[mt][nt], 0, 0, 0);
    }
#pragma unroll
    for (int mt = 0; mt < 4; mt++) {
#pragma unroll
        for (int r = 0; r < 4; r++) {
            int grow = m0 + wm * 64 + mt * 16 + (lane >> 4) * 4 + r;
            if (grow >= M) continue;
#pragma unroll
            for (int nt = 0; nt < 4; nt++) {
                int gcol = n0 + wn * 64 + nt * 16 + (lane & 15);
                Cb[(size_t)grow * Nc + gcol] = f2bf(acc[mt][nt][r]);
            }
        }
    }
}

// ---------------- attention scores (wave per node) ----------------
__global__ __launch_bounds__(256) void s_kernel(
    const unsigned short* __restrict__ xw,
    const unsigned short* __restrict__ a_src,
    const unsigned short* __restrict__ a_dst,
    float* __restrict__ s_src, float* __restrict__ s_dst)
{
    int wid = (blockIdx.x * 256 + threadIdx.x) >> 6;
    int lane = threadIdx.x & 63;
    if (wid >= N_NODES) return;
    int f = lane * 4;
    shortx4 xv = *(const shortx4*)(xw + (size_t)wid * DIM + f);
    shortx4 asv = *(const shortx4*)(a_src + f);
    shortx4 adv = *(const shortx4*)(a_dst + f);
    float x0 = bf2f((unsigned short)xv.x), x1 = bf2f((unsigned short)xv.y);
    float x2 = bf2f((unsigned short)xv.z), x3 = bf2f((unsigned short)xv.w);
    float ps = x0 * bf2f((unsigned short)asv.x) + x1 * bf2f((unsigned short)asv.y)
             + x2 * bf2f((unsigned short)asv.z) + x3 * bf2f((unsigned short)asv.w);
    float pd = x0 * bf2f((unsigned short)adv.x) + x1 * bf2f((unsigned short)adv.y)
             + x2 * bf2f((unsigned short)adv.z) + x3 * bf2f((unsigned short)adv.w);
    for (int s = 1; s < 16; s <<= 1) { ps += __shfl_xor(ps, s); pd += __shfl_xor(pd, s); }
    if ((lane & 15) == 0) {
        int h = lane >> 4;
        s_src[(size_t)wid * 4 + h] = ps;
        s_dst[(size_t)wid * 4 + h] = pd;
    }
}

// ---------------- fused per-node online-softmax + aggregation (one wave per node) ----------------
__global__ __launch_bounds__(256) void attn_agg(
    const unsigned short* __restrict__ xw,
    const float* __restrict__ s_src, const float* __restrict__ s_dst,
    const int* __restrict__ off, const int* __restrict__ eidx,
    const int* __restrict__ rown, const unsigned short* __restrict__ bias,
    unsigned short* __restrict__ h_bf, float* __restrict__ h_f32,
    float* __restrict__ attn_acc, float* __restrict__ attn_out,
    const unsigned short* __restrict__ wn, const unsigned short* __restrict__ bn,
    float* __restrict__ node_out, int layer)
{
    int wid = (blockIdx.x * 256 + threadIdx.x) >> 6;
    int lane = threadIdx.x & 63;
    if (wid >= N_NODES) return;
    int n = wid;
    floatx4 sdv = *(const floatx4*)(s_dst + (size_t)n * 4);
    int base = off[n];
    int deg = off[n + 1] - base;

    // online (max, denom)
    float m0 = -1e30f, m1 = -1e30f, m2 = -1e30f, m3 = -1e30f;
    float d0 = 0.f, d1 = 0.f, d2 = 0.f, d3 = 0.f;
    for (int i = lane; i < deg; i += 64) {
        int e = eidx[base + i];
        int r = (e < N_EDGES) ? rown[e] : (e - N_EDGES);
        floatx4 sv = *(const floatx4*)(s_src + (size_t)r * 4);
        float t0 = sv.x + sdv.x; t0 = t0 > 0.f ? t0 : NEG_SLOPE * t0;
        float t1 = sv.y + sdv.y; t1 = t1 > 0.f ? t1 : NEG_SLOPE * t1;
        float t2 = sv.z + sdv.z; t2 = t2 > 0.f ? t2 : NEG_SLOPE * t2;
        float t3 = sv.w + sdv.w; t3 = t3 > 0.f ? t3 : NEG_SLOPE * t3;
        float nm;
        nm = fmaxf(m0, t0); d0 = d0 * __expf(m0 - nm) + __expf(t0 - nm); m0 = nm;
        nm = fmaxf(m1, t1); d1 = d1 * __expf(m1 - nm) + __expf(t1 - nm); m1 = nm;
        nm = fmaxf(m2, t2); d2 = d2 * __expf(m2 - nm) + __expf(t2 - nm); m2 = nm;
        nm = fmaxf(m3, t3); d3 = d3 * __expf(m3 - nm) + __expf(t3 - nm); m3 = nm;
    }
    for (int s = 1; s < 64; s <<= 1) {
        float om, od, nm;
        om = __shfl_xor(m0, s); od = __shfl_xor(d0, s);
        nm = fmaxf(m0, om); d0 = d0 * __expf(m0 - nm) + od * __expf(om - nm); m0 = nm;
        om = __shfl_xor(m1, s); od = __shfl_xor(d1, s);
        nm = fmaxf(m1, om); d1 = d1 * __expf(m1 - nm) + od * __expf(om - nm); m1 = nm;
        om = __shfl_xor(m2, s); od = __shfl_xor(d2, s);
        nm = fmaxf(m2, om); d2 = d2 * __expf(m2 - nm) + od * __expf(om - nm); m2 = nm;
        om = __shfl_xor(m3, s); od = __shfl_xor(d3, s);
        nm = fmaxf(m3, om); d3 = d3 * __expf(m3 - nm) + od * __expf(om - nm); m3 = nm;
    }
    float i0 = 1.f / d0, i1 = 1.f / d1, i2 = 1.f / d2, i3 = 1.f / d3;

    // alpha + weighted feature gather
    int hl = lane >> 4;
    int f = lane * 4;
    float acc0 = 0.f, acc1 = 0.f, acc2 = 0.f, acc3 = 0.f;
    for (int c0 = 0; c0 < deg; c0 += 64) {
        int i = c0 + lane;
        int r = 0; float a0 = 0.f, a1 = 0.f, a2 = 0.f, a3 = 0.f;
        if (i < deg) {
            int e = eidx[base + i];
            r = (e < N_EDGES) ? rown[e] : (e - N_EDGES);
            floatx4 sv = *(const floatx4*)(s_src + (size_t)r * 4);
            float t0 = sv.x + sdv.x; t0 = t0 > 0.f ? t0 : NEG_SLOPE * t0;
            float t1 = sv.y + sdv.y; t1 = t1 > 0.f ? t1 : NEG_SLOPE * t1;
            float t2 = sv.z + sdv.z; t2 = t2 > 0.f ? t2 : NEG_SLOPE * t2;
            float t3 = sv.w + sdv.w; t3 = t3 > 0.f ? t3 : NEG_SLOPE * t3;
            a0 = __expf(t0 - m0) * i0; a1 = __expf(t1 - m1) * i1;
            a2 = __expf(t2 - m2) * i2; a3 = __expf(t3 - m3) * i3;
            float suma = 0.125f * (a0 + a1 + a2 + a3);
            if (layer == 0) attn_acc[e] = suma;
            else            attn_out[e] = attn_acc[e] + suma;
        }
        int cntc = deg - c0; if (cntc > 64) cntc = 64;
        for (int j = 0; j < cntc; j++) {
            int rj = __shfl(r, j);
            float b0 = __shfl(a0, j), b1 = __shfl(a1, j), b2 = __shfl(a2, j), b3 = __shfl(a3, j);
            float al = (hl == 0) ? b0 : ((hl == 1) ? b1 : ((hl == 2) ? b2 : b3));
            shortx4 xv = *(const shortx4*)(xw + (size_t)rj * DIM + f);
            acc0 += al * bf2f((unsigned short)xv.x);
            acc1 += al * bf2f((unsigned short)xv.y);
            acc2 += al * bf2f((unsigned short)xv.z);
            acc3 += al * bf2f((unsigned short)xv.w);
        }
    }
    shortx4 bv = *(const shortx4*)(bias + f);
    float o0 = acc0 + bf2f((unsigned short)bv.x);
    float o1 = acc1 + bf2f((unsigned short)bv.y);
    float o2 = acc2 + bf2f((unsigned short)bv.z);
    float o3 = acc3 + bf2f((unsigned short)bv.w);
    o0 = o0 > 0.f ? o0 : (__expf(o0) - 1.f);
    o1 = o1 > 0.f ? o1 : (__expf(o1) - 1.f);
    o2 = o2 > 0.f ? o2 : (__expf(o2) - 1.f);
    o3 = o3 > 0.f ? o3 : (__expf(o3) - 1.f);
    if (h_bf) {
        shortx4 pk;
        pk.x = (short)f2bf(o0); pk.y = (short)f2bf(o1);
        pk.z = (short)f2bf(o2); pk.w = (short)f2bf(o3);
        *(shortx4*)(h_bf + (size_t)n * DIM + f) = pk;
    }
    if (h_f32) {
        floatx4 pv; pv.x = o0; pv.y = o1; pv.z = o2; pv.w = o3;
        *(floatx4*)(h_f32 + (size_t)n * DIM + f) = pv;
    }
    if (wn) {   // fused node predictor
        shortx4 wv = *(const shortx4*)(wn + f);
        float p = o0 * bf2f((unsigned short)wv.x) + o1 * bf2f((unsigned short)wv.y)
                + o2 * bf2f((unsigned short)wv.z) + o3 * bf2f((unsigned short)wv.w);
        for (int s = 1; s < 64; s <<= 1) p += __shfl_xor(p, s);
        if (lane == 0) node_out[n] = p + bf2f(bn[0]);
    }
}

// ---------------- edge predictor, source-CSR, 4-way unrolled ----------------
__global__ __launch_bounds__(256) void edge_pred_src(
    const unsigned short* __restrict__ h,   // bf16 [N,256]
    const unsigned short* __restrict__ V,   // bf16 [N,768] = V0|V1|V2
    const int* __restrict__ soff, const int* __restrict__ seidx,
    const int* __restrict__ coln,
    const unsigned short* __restrict__ bb, float* __restrict__ outp)
{
    int wid = (blockIdx.x * 256 + threadIdx.x) >> 6;
    int lane = threadIdx.x & 63;
    if (wid >= N_NODES) return;
    int s = wid;
    int base = soff[s];
    int deg = soff[s + 1] - base;
    if (deg == 0) return;
    int f = lane * 4;
    const unsigned short* vrow = V + (size_t)s * 768;
    shortx4 v0 = *(const shortx4*)(vrow + 0   + f);
    shortx4 v1 = *(const shortx4*)(vrow + 256 + f);
    shortx4 v2 = *(const shortx4*)(vrow + 512 + f);
    float w00 = bf2f((unsigned short)v0.x), w01 = bf2f((unsigned short)v0.y),
          w02 = bf2f((unsigned short)v0.z), w03 = bf2f((unsigned short)v0.w);
    float w10 = bf2f((unsigned short)v1.x), w11 = bf2f((unsigned short)v1.y),
          w12 = bf2f((unsigned short)v1.z), w13 = bf2f((unsigned short)v1.w);
    float w20 = bf2f((unsigned short)v2.x), w21 = bf2f((unsigned short)v2.y),
          w22 = bf2f((unsigned short)v2.z), w23 = bf2f((unsigned short)v2.w);
    float bb0 = bf2f(bb[0]), bb1 = bf2f(bb[1]), bb2 = bf2f(bb[2]);

    int i = 0;
    for (; i + 4 <= deg; i += 4) {
        int e0 = seidx[base + i + 0], e1 = seidx[base + i + 1];
        int e2 = seidx[base + i + 2], e3 = seidx[base + i + 3];
        int t0 = coln[e0], t1 = coln[e1], t2 = coln[e2], t3 = coln[e3];
        shortx4 h0v = *(const shortx4*)(h + (size_t)t0 * DIM + f);
        shortx4 h1v = *(const shortx4*)(h + (size_t)t1 * DIM + f);
        shortx4 h2v = *(const shortx4*)(h + (size_t)t2 * DIM + f);
        shortx4 h3v = *(const shortx4*)(h + (size_t)t3 * DIM + f);
        float a0 = bf2f((unsigned short)h0v.x), a1 = bf2f((unsigned short)h0v.y),
              a2 = bf2f((unsigned short)h0v.z), a3 = bf2f((unsigned short)h0v.w);
        float b0 = bf2f((unsigned short)h1v.x), b1 = bf2f((unsigned short)h1v.y),
              b2 = bf2f((unsigned short)h1v.z), b3 = bf2f((unsigned short)h1v.w);
        float c0 = bf2f((unsigned short)h2v.x), c1 = bf2f((unsigned short)h2v.y),
              c2 = bf2f((unsigned short)h2v.z), c3 = bf2f((unsigned short)h2v.w);
        float d0 = bf2f((unsigned short)h3v.x), d1 = bf2f((unsigned short)h3v.y),
              d2 = bf2f((unsigned short)h3v.z), d3 = bf2f((unsigned short)h3v.w);
        float p00 = a0*w00 + a1*w01 + a2*w02 + a3*w03;
        float p01 = a0*w10 + a1*w11 + a2*w12 + a3*w13;
        float p02 = a0*w20 + a1*w21 + a2*w22 + a3*w23;
        float p10 = b0*w00 + b1*w01 + b2*w02 + b3*w03;
        float p11 = b0*w10 + b1*w11 + b2*w12 + b3*w13;
        float p12 = b0*w20 + b1*w21 + b2*w22 + b3*w23;
        float p20 = c0*w00 + c1*w01 + c2*w02 + c3*w03;
        float p21 = c0*w10 + c1*w11 + c2*w12 + c3*w13;
        float p22 = c0*w20 + c1*w21 + c2*w22 + c3*w23;
        float p30 = d0*w00 + d1*w01 + d2*w02 + d3*w03;
        float p31 = d0*w10 + d1*w11 + d2*w12 + d3*w13;
        float p32 = d0*w20 + d1*w21 + d2*w22 + d3*w23;
        for (int m = 1; m < 64; m <<= 1) {
            p00 += __shfl_xor(p00, m); p01 += __shfl_xor(p01, m); p02 += __shfl_xor(p02, m);
            p10 += __shfl_xor(p10, m); p11 += __shfl_xor(p11, m); p12 += __shfl_xor(p12, m);
            p20 += __shfl_xor(p20, m); p21 += __shfl_xor(p21, m); p22 += __shfl_xor(p22, m);
            p30 += __shfl_xor(p30, m); p31 += __shfl_xor(p31, m); p32 += __shfl_xor(p32, m);
        }
        if (lane == 0) {
            outp[(size_t)e0 * 3 + 0] = p00 + bb0;
            outp[(size_t)e0 * 3 + 1] = p01 + bb1;
            outp[(size_t)e0 * 3 + 2] = p02 + bb2;
            outp[(size_t)e1 * 3 + 0] = p10 + bb0;
            outp[(size_t)e1 * 3 + 1] = p11 + bb1;
            outp[(size_t)e1 * 3 + 2] = p12 + bb2;
            outp[(size_t)e2 * 3 + 0] = p20 + bb0;
            outp[(size_t)e2 * 3 + 1] = p21 + bb1;
            outp[(size_t)e2 * 3 + 2] = p22 + bb2;
            outp[(size_t)e3 * 3 + 0] = p30 + bb0;
            outp[(size_t)e3 * 3 + 1] = p31 + bb1;
            outp[(size_t)e3 * 3 + 2] = p32 + bb2;
        }
    }
    for (; i < deg; i++) {
        int e = seidx[base + i];
        int t = coln[e];
        shortx4 hv = *(const shortx4*)(h + (size_t)t * DIM + f);
        float h0 = bf2f((unsigned short)hv.x), h1 = bf2f((unsigned short)hv.y);
        float h2 = bf2f((unsigned short)hv.z), h3 = bf2f((unsigned short)hv.w);
        float p0 = h0 * w00 + h1 * w01 + h2 * w02 + h3 * w03;
        float p1 = h0 * w10 + h1 * w11 + h2 * w12 + h3 * w13;
        float p2 = h0 * w20 + h1 * w21 + h2 * w22 + h3 * w23;
        for (int m = 1; m < 64; m <<= 1) {
            p0 += __shfl_xor(p0, m);
            p1 += __shfl_xor(p1, m);
            p2 += __shfl_xor(p2, m);
        }
        if (lane == 0) {
            outp[(size_t)e * 3 + 0] = p0 + bb0;
            outp[(size_t)e * 3 + 1] = p1 + bb1;
            outp[(size_t)e * 3 + 2] = p2 + bb2;
        }
    }
}

extern "C" void kernel_launch(void* const* d_in, const int* in_sizes, int n_in,
                              void* d_out, int out_size, void* d_ws, size_t ws_size,
                              hipStream_t stream) {
    const void* x_raw  = d_in[0];
    const int*  ei_raw = (const int*)d_in[1];
    float* out = (float*)d_out;

    char* w = (char*)d_ws;
    size_t off_b = 0;
    auto alloc = [&](size_t bytes) -> char* {
        char* p = w + off_b; off_b = (off_b + bytes + 255) & ~(size_t)255; return p;
    };
    int*            flags  = (int*)alloc(256);
    unsigned short* buf0   = (unsigned short*)alloc((size_t)N_NODES * DIM * 2); // x_bf -> h bf16
    unsigned short* R      = (unsigned short*)alloc((size_t)N_NODES * 768 * 2); // xw|h1, later V
    unsigned short* buf1   = R;
    unsigned short* buf2   = R + (size_t)N_NODES * DIM;
    unsigned short* V      = R;
    float*          ssrc   = (float*)alloc((size_t)N_NODES * 4 * 4);
    float*          sdst   = (float*)alloc((size_t)N_NODES * 4 * 4);
    float*          attn   = (float*)alloc((size_t)ETOT * 4);
    int*            cnt    = (int*)alloc((size_t)4 * N_NODES * 4);  // cnt,cursor,scnt,scursor
    int*            cursor = cnt + N_NODES;
    int*            scnt   = cnt + 2 * N_NODES;
    int*            scursor= cnt + 3 * N_NODES;
    int*            offs   = (int*)alloc((size_t)(N_NODES + 1) * 4);
    int*            soffs  = (int*)alloc((size_t)(N_NODES + 1) * 4);
    int*            part   = (int*)alloc(512 * 4);                  // 2 x 256 partials
    int*            spart  = part + 256;
    int*            eidx   = (int*)alloc((size_t)ETOT * 4);
    int*            seidx  = (int*)alloc((size_t)N_EDGES * 4);
    int*            rown   = (int*)alloc((size_t)N_EDGES * 4);
    int*            coln   = (int*)alloc((size_t)N_EDGES * 4);
    unsigned short* BT     = (unsigned short*)alloc((size_t)5 * 65536 * 2);
    unsigned short* small  = (unsigned short*)alloc(2048 * 2);
    // small: a1s@0 a1d@256 b1@512 a2s@768 a2d@1024 b2@1280 Wn@1536 bn@1792 bb@1793

    float* out_node = out;              // [50000]
    float* out_edge = out + 50000;      // [800000,3]
    float* out_h    = out + 2450000;    // [50000,256]
    float* out_attn = out + 15250000;   // [850000]

    int eb = (ETOT + 255) / 256;
    int e0b = (N_EDGES + 255) / 256;
    int node_wave_blocks = (N_NODES * 64) / 256;
    dim3 gg((N_NODES + 127) / 128, 2);
    dim3 gv((N_NODES + 127) / 128, 6);

    detect_kernel<<<1, 256, 0, stream>>>((const unsigned short*)x_raw, ei_raw, flags);
    norm_x<<<12500, 256, 0, stream>>>(x_raw, buf0, flags);
    norm_small<<<1, 256, 0, stream>>>(d_in[3],  small + 0,    256, flags);
    norm_small<<<1, 256, 0, stream>>>(d_in[4],  small + 256,  256, flags);
    norm_small<<<1, 256, 0, stream>>>(d_in[5],  small + 512,  256, flags);
    norm_small<<<1, 256, 0, stream>>>(d_in[7],  small + 768,  256, flags);
    norm_small<<<1, 256, 0, stream>>>(d_in[8],  small + 1024, 256, flags);
    norm_small<<<1, 256, 0, stream>>>(d_in[9],  small + 1280, 256, flags);
    norm_small<<<1, 256, 0, stream>>>(d_in[10], small + 1536, 256, flags);
    norm_small<<<1, 256, 0, stream>>>(d_in[11], small + 1792, 1,   flags);
    norm_small<<<1, 256, 0, stream>>>(d_in[13], small + 1793, 3,   flags);
    norm_edges<<<3125, 256, 0, stream>>>(ei_raw, rown, coln, flags);
    transpose_kernel<<<1280, 256, 0, stream>>>(d_in[2], d_in[6], d_in[12], BT, flags);

    zero_kernel<<<(4 * N_NODES + 255) / 256, 256, 0, stream>>>(cnt, 4 * N_NODES);
    count_kernel<<<eb, 256, 0, stream>>>(coln, cnt);
    count_src<<<e0b, 256, 0, stream>>>(rown, scnt);
    // hierarchical scans (dst then src)
    scan_part<<<NBLK, 256, 0, stream>>>(cnt, part, N_NODES);
    scan_small<<<1, 256, 0, stream>>>(part, NBLK);
    scan_final<<<NBLK, 256, 0, stream>>>(cnt, part, offs, N_NODES, ETOT);
    scan_part<<<NBLK, 256, 0, stream>>>(scnt, spart, N_NODES);
    scan_small<<<1, 256, 0, stream>>>(spart, NBLK);
    scan_final<<<NBLK, 256, 0, stream>>>(scnt, spart, soffs, N_NODES, N_EDGES);
    fill_kernel<<<eb, 256, 0, stream>>>(coln, offs, cursor, eidx);
    fill_src<<<e0b, 256, 0, stream>>>(rown, soffs, scursor, seidx);

    // ---- layer 1 ----
    gemm256<<<gg, 256, 0, stream>>>(buf0, BT, buf1, N_NODES, 256);
    s_kernel<<<node_wave_blocks, 256, 0, stream>>>(buf1, small + 0, small + 256, ssrc, sdst);
    attn_agg<<<node_wave_blocks, 256, 0, stream>>>(buf1, ssrc, sdst, offs, eidx, rown,
                                                   small + 512, buf2, nullptr, attn, nullptr,
                                                   nullptr, nullptr, nullptr, 0);

    // ---- layer 2 (+ fused node_pred) ----
    gemm256<<<gg, 256, 0, stream>>>(buf2, BT + 65536, buf1, N_NODES, 256);
    s_kernel<<<node_wave_blocks, 256, 0, stream>>>(buf1, small + 768, small + 1024, ssrc, sdst);
    attn_agg<<<node_wave_blocks, 256, 0, stream>>>(buf1, ssrc, sdst, offs, eidx, rown,
                                                   small + 1280, buf0, out_h, attn, out_attn,
                                                   small + 1536, small + 1792, out_node, 1);

    // ---- edge head: V[N,768] in one GEMM; source-CSR edge dots ----
    gemm256<<<gv, 256, 0, stream>>>(buf0, BT + 2 * 65536, V, N_NODES, 768);
    edge_pred_src<<<node_wave_blocks, 256, 0, stream>>>(buf0, V, soffs, seidx, coln,
                                                        small + 1793, out_edge);
}